// Round 10
// baseline (658.195 us; speedup 1.0000x reference)
//
#include <hip/hip_runtime.h>
#include <math.h>

// ---------------------------------------------------------------------------
// KGMC SAGE: 4x SAGEConv(mean) + tanh over (N=200k, E=3.2M, d=32), then a
// 4096-pair MLP head.
//   CSR build: bucketed counting sort, padded bucket slots (unchanged).
//   Layers (R8): inter-layer feature tables stored in fp16 ([N][32] ushort,
//   ping-pong in d_ws) — halves the per-edge gather bytes (128B -> 64B row)
//   which R7 showed to be partially L2-miss/L3-BW bound. Self term + matmul
//   + outputs remain f32. Gather loop otherwise identical to R7 (shfl csr
//   broadcast, 8-deep unroll).
//   (R9: resubmit — GPU acquisition timeout, R8 source never executed.)
// ---------------------------------------------------------------------------

constexpr int BN       = 512;       // nodes per bucket
constexpr int LOG_BN   = 9;
constexpr int MAXBUCK  = 512;       // supports N <= 262144 (src fits 18 bits)
constexpr int EPB      = 8192;      // edges per coarse block
constexpr int SRC_BITS = 18;
constexpr int SRC_MASK = (1 << SRC_BITS) - 1;
constexpr int BCAP_LOG = 14;        // padded bucket capacity 16384 (avg ~8184)

static __device__ inline float h2f(ushort u) {
    _Float16 h;
    __builtin_memcpy(&h, &u, 2);
    return (float)h;
}
static __device__ inline ushort f2h(float f) {
    _Float16 h = (_Float16)f;
    ushort u;
    __builtin_memcpy(&u, &h, 2);
    return u;
}

// One pass over edges: per-block LDS histogram -> reserve runs in padded
// bucket regions (bucket_cur also accumulates final counts) -> scatter packed.
__global__ __launch_bounds__(256)
void coarse_scatter(const int* __restrict__ src, const int* __restrict__ dst,
                    int* __restrict__ bucket_cur, int* __restrict__ packed,
                    int E, int nbuck) {
    __shared__ int h[MAXBUCK];
    int t = threadIdx.x;
    for (int i = t; i < nbuck; i += 256) h[i] = 0;
    __syncthreads();
    int base = blockIdx.x * EPB;
    int end  = min(base + EPB, E);
    for (int j = base + t; j < end; j += 256)
        atomicAdd(&h[dst[j] >> LOG_BN], 1);
    __syncthreads();
    for (int i = t; i < nbuck; i += 256) {
        int c = h[i];
        if (c) h[i] = atomicAdd(&bucket_cur[i], c);   // within-bucket offset
    }
    __syncthreads();
    for (int j = base + t; j < end; j += 256) {
        int d  = dst[j];
        int bk = d >> LOG_BN;
        int p  = atomicAdd(&h[bk], 1);
        packed[(bk << BCAP_LOG) + p] = ((d & (BN - 1)) << SRC_BITS) | src[j];
    }
}

__global__ __launch_bounds__(512)
void bucket_scan(const int* __restrict__ cnts, int* __restrict__ bucket_base,
                 int nbuck) {
    __shared__ int sh[512];
    int t = threadIdx.x;
    int v = (t < nbuck) ? cnts[t] : 0;
    sh[t] = v;
    __syncthreads();
    for (int off = 1; off < 512; off <<= 1) {
        int u = (t >= off) ? sh[t - off] : 0;
        __syncthreads();
        sh[t] += u;
        __syncthreads();
    }
    if (t < nbuck) bucket_base[t] = sh[t] - v;        // exclusive prefix
}

// One block per bucket: per-node count+scan+cursors in LDS; csr writes land
// in this block's contiguous output window.
__global__ __launch_bounds__(512)
void fine_fill(const int* __restrict__ packed, const int* __restrict__ bucket_cnt,
               const int* __restrict__ bucket_base, int* __restrict__ rowstart,
               int* __restrict__ csr, int N, int E) {
    __shared__ int cnt_[BN];
    __shared__ int cur_[BN];
    __shared__ int sh[512];
    int b = blockIdx.x, t = threadIdx.x;
    int cnt   = bucket_cnt[b];
    int obase = bucket_base[b];
    const int* __restrict__ pk = packed + ((size_t)b << BCAP_LOG);
    cnt_[t] = 0;
    __syncthreads();
    for (int j = t; j < cnt; j += 512)
        atomicAdd(&cnt_[pk[j] >> SRC_BITS], 1);
    __syncthreads();
    int v = cnt_[t];
    sh[t] = v;
    __syncthreads();
    for (int off = 1; off < 512; off <<= 1) {
        int u = (t >= off) ? sh[t - off] : 0;
        __syncthreads();
        sh[t] += u;
        __syncthreads();
    }
    int excl = sh[t] - v;
    int node = b * BN + t;
    if (node < N) rowstart[node] = obase + excl;
    cur_[t] = obase + excl;
    __syncthreads();
    for (int j = t; j < cnt; j += 512) {
        int pv = pk[j];
        int p  = atomicAdd(&cur_[pv >> SRC_BITS], 1);
        csr[p] = pv & SRC_MASK;
    }
    if (b == 0 && t == 0) rowstart[N] = E;
}

// f32 -> f16 convert (2 elems/thread), for the layer-0 input table.
__global__ __launch_bounds__(256)
void cvt_f32_f16(const float* __restrict__ in, ushort* __restrict__ out, int n2) {
    int i = blockIdx.x * 256 + threadIdx.x;
    if (i < n2) {
        float2 v = ((const float2*)in)[i];
        ushort2 o;
        o.x = f2h(v.x);
        o.y = f2h(v.y);
        ((ushort2*)out)[i] = o;
    }
}

// Fused SAGE layer: mean-aggregate + h@Ws + mean@Wn + b, tanh.
// Input features from f16 table ht_in [N][32]; f32 output into cs column
// slice; optionally writes next layer's f16 table.
template <int GROUPS, bool WRITE_F16>
__global__ __launch_bounds__(GROUPS * 32)
void sage_layer(const ushort* __restrict__ ht_in,
                float* __restrict__ h_out, int out_off,
                ushort* __restrict__ ht_out,
                const int* __restrict__ rowstart, const int* __restrict__ csr,
                const float* __restrict__ Ws, const float* __restrict__ Wn,
                const float* __restrict__ b, int N) {
    __shared__ float2 WS[32 * 32];       // interleaved (Ws, Wn)
    __shared__ float2 HM[GROUPS][32];    // per-group (h, mean) row
    __shared__ float  bS[32];

    int tid = threadIdx.x;
    for (int i = tid; i < 1024; i += GROUPS * 32)
        WS[i] = make_float2(Ws[i], Wn[i]);
    if (tid < 32) bS[tid] = b[tid];
    __syncthreads();

    int g = tid >> 5;
    int f = tid & 31;
    int n = blockIdx.x * GROUPS + g;
    if (n >= N) return;

    const ushort* __restrict__ hb = ht_in + f;   // per-lane base

    float hval = h2f(hb[(unsigned)(n << 5)]);

    int start = rowstart[n];
    int end   = rowstart[n + 1];
    float acc0 = 0.f, acc1 = 0.f;
    int j = start;
    while (j < end) {
        int cnt = min(32, end - j);
        // one coalesced lane-strided csr load per 32 edges
        int cv = (f < cnt) ? csr[j + f] : 0;
        int k = 0;
        for (; k + 8 <= cnt; k += 8) {
            int s0 = __shfl(cv, k + 0, 32);
            int s1 = __shfl(cv, k + 1, 32);
            int s2 = __shfl(cv, k + 2, 32);
            int s3 = __shfl(cv, k + 3, 32);
            int s4 = __shfl(cv, k + 4, 32);
            int s5 = __shfl(cv, k + 5, 32);
            int s6 = __shfl(cv, k + 6, 32);
            int s7 = __shfl(cv, k + 7, 32);
            ushort u0 = hb[(unsigned)(s0 << 5)];
            ushort u1 = hb[(unsigned)(s1 << 5)];
            ushort u2 = hb[(unsigned)(s2 << 5)];
            ushort u3 = hb[(unsigned)(s3 << 5)];
            ushort u4 = hb[(unsigned)(s4 << 5)];
            ushort u5 = hb[(unsigned)(s5 << 5)];
            ushort u6 = hb[(unsigned)(s6 << 5)];
            ushort u7 = hb[(unsigned)(s7 << 5)];
            acc0 += (h2f(u0) + h2f(u1)) + (h2f(u2) + h2f(u3));
            acc1 += (h2f(u4) + h2f(u5)) + (h2f(u6) + h2f(u7));
        }
        for (; k < cnt; ++k) {
            int s = __shfl(cv, k, 32);
            acc0 += h2f(hb[(unsigned)(s << 5)]);
        }
        j += cnt;
    }
    float acc = acc0 + acc1;

    int deg = end - start;
    float mval = acc / (float)(deg > 0 ? deg : 1);

    // share (h, mean) within the 32-lane group via LDS (same wave)
    HM[g][f] = make_float2(hval, mval);
    __builtin_amdgcn_wave_barrier();

    float out = bS[f];
#pragma unroll
    for (int k = 0; k < 32; ++k) {
        float2 hm = HM[g][k];            // broadcast
        float2 w  = WS[k * 32 + f];      // 8B stride, 2-way free
        out += hm.x * w.x + hm.y * w.y;
    }
    float r = tanhf(out);
    h_out[(unsigned)((n << 7) + out_off + f)] = r;
    if (WRITE_F16)
        ht_out[(unsigned)(n << 5) + f] = f2h(r);
}

// Pair MLP head: hdn = relu([cs[u], cs[i]] @ W1 + bl1); out = sigmoid(hdn@W2+bl2)
template <int PPB>
__global__ __launch_bounds__(128)
void pair_mlp(const float* __restrict__ cs, const int* __restrict__ uidx,
              const int* __restrict__ iidx, const float* __restrict__ W1,
              const float* __restrict__ bl1, const float* __restrict__ W2,
              const float* __restrict__ bl2, float* __restrict__ score, int P) {
    __shared__ float sp[PPB][256];
    __shared__ float wsum[2][PPB];
    int j  = threadIdx.x;
    int p0 = blockIdx.x * PPB;

    for (int q = 0; q < PPB; ++q) {
        int p = p0 + q;
        if (p < P) {
            int u  = uidx[p];
            int it = iidx[p];
            sp[q][j]       = cs[(size_t)u  * 128 + j];
            sp[q][128 + j] = cs[(size_t)it * 128 + j];
        } else {
            sp[q][j] = 0.f;
            sp[q][128 + j] = 0.f;
        }
    }
    __syncthreads();

    float acc[PPB];
    float bb = bl1[j];
#pragma unroll
    for (int q = 0; q < PPB; ++q) acc[q] = bb;

    for (int i = 0; i < 256; ++i) {
        float w = W1[i * 128 + j];
#pragma unroll
        for (int q = 0; q < PPB; ++q) acc[q] += sp[q][i] * w;
    }

    float w2   = W2[j];
    int   wave = j >> 6;
    int   lane = j & 63;
#pragma unroll
    for (int q = 0; q < PPB; ++q) {
        float v = fmaxf(acc[q], 0.f) * w2;
#pragma unroll
        for (int o = 32; o > 0; o >>= 1) v += __shfl_xor(v, o, 64);
        if (lane == 0) wsum[wave][q] = v;
    }
    __syncthreads();
    if (j < PPB) {
        int p = p0 + j;
        if (p < P) {
            float t = wsum[0][j] + wsum[1][j] + bl2[0];
            score[p] = 1.f / (1.f + expf(-t));
        }
    }
}

extern "C" void kernel_launch(void* const* d_in, const int* in_sizes, int n_in,
                              void* d_out, int out_size, void* d_ws, size_t ws_size,
                              hipStream_t stream) {
    const float* x    = (const float*)d_in[0];
    const int*   src  = (const int*)d_in[1];
    const int*   dst  = (const int*)d_in[2];
    const int*   uidx = (const int*)d_in[3];
    const int*   iidx = (const int*)d_in[4];
    const float* Ws[4] = {(const float*)d_in[5], (const float*)d_in[8],
                          (const float*)d_in[11], (const float*)d_in[14]};
    const float* Wn[4] = {(const float*)d_in[6], (const float*)d_in[9],
                          (const float*)d_in[12], (const float*)d_in[15]};
    const float* bb[4] = {(const float*)d_in[7], (const float*)d_in[10],
                          (const float*)d_in[13], (const float*)d_in[16]};
    const float* W1  = (const float*)d_in[17];
    const float* bl1 = (const float*)d_in[18];
    const float* W2  = (const float*)d_in[19];
    const float* bl2 = (const float*)d_in[20];

    const int N = in_sizes[0] / 32;
    const int E = in_sizes[1];
    const int P = in_sizes[3];
    const int NBUCK = (N + BN - 1) / BN;            // 391 for N=200k
    const int NEB   = (E + EPB - 1) / EPB;

    // workspace (ints): ~39 MB total
    int* ws_i        = (int*)d_ws;
    size_t o         = 0;
    int* bucket_cur  = ws_i + o; o += MAXBUCK;      // counts after scatter
    int* bucket_base = ws_i + o; o += MAXBUCK;
    int* rowstart    = ws_i + o; o += (size_t)((N + 1 + 63) & ~63);
    int* csr         = ws_i + o; o += (size_t)E;
    ushort* ht0      = (ushort*)(ws_i + o); o += (size_t)(N * 16);  // [N][32] f16
    ushort* ht1      = (ushort*)(ws_i + o); o += (size_t)(N * 16);

    float* score = (float*)d_out;
    float* cs    = score + P;                       // concat_states [N,128]
    // padded packed edges live in the tail of d_out: consumed by fine_fill
    // before any sage layer writes that region.
    int* packed  = (int*)d_out + ((size_t)out_size - ((size_t)NBUCK << BCAP_LOG));

    // --- build CSR (dst -> list of src) ---
    hipMemsetAsync(bucket_cur, 0, sizeof(int) * MAXBUCK, stream);
    coarse_scatter<<<NEB, 256, 0, stream>>>(src, dst, bucket_cur, packed, E, NBUCK);
    bucket_scan<<<1, 512, 0, stream>>>(bucket_cur, bucket_base, NBUCK);
    fine_fill<<<NBUCK, 512, 0, stream>>>(packed, bucket_cur, bucket_base,
                                         rowstart, csr, N, E);

    // --- layer-0 input table: x -> f16 ---
    cvt_f32_f16<<<(N * 16 + 255) / 256, 256, 0, stream>>>(x, ht0, N * 16);

    // --- 4 fused SAGE layers, writing concat_states slices + f16 tables ---
    sage_layer<8, true><<<(N + 7) / 8, 256, 0, stream>>>(
        ht0, cs, 0, ht1, rowstart, csr, Ws[0], Wn[0], bb[0], N);
    sage_layer<8, true><<<(N + 7) / 8, 256, 0, stream>>>(
        ht1, cs, 32, ht0, rowstart, csr, Ws[1], Wn[1], bb[1], N);
    sage_layer<8, true><<<(N + 7) / 8, 256, 0, stream>>>(
        ht0, cs, 64, ht1, rowstart, csr, Ws[2], Wn[2], bb[2], N);
    sage_layer<8, false><<<(N + 7) / 8, 256, 0, stream>>>(
        ht1, cs, 96, (ushort*)nullptr, rowstart, csr, Ws[3], Wn[3], bb[3], N);

    // --- pair MLP head ---
    pair_mlp<8><<<(P + 7) / 8, 128, 0, stream>>>(
        cs, uidx, iidx, W1, bl1, W2, bl2, score, P);
}

// Round 11
// 622.094 us; speedup vs baseline: 1.0580x; 1.0580x over previous
//
#include <hip/hip_runtime.h>
#include <math.h>

// ---------------------------------------------------------------------------
// KGMC SAGE: 4x SAGEConv(mean) + tanh over (N=200k, E=3.2M, d=32), then a
// 4096-pair MLP head.
//   CSR build: bucketed counting sort, padded bucket slots (unchanged).
//   Layers: fp16 feature tables (R8). R10: gather loop restructured into
//   3 batched phases per 16-edge chunk (bpermutes | loads | adds) — R8 was
//   latency-bound on per-8-edge bpermute->load wait serialization (~650cy
//   x4 per 32 edges matched the measured 99us). Loads are branchless (dead
//   lanes read row 0, L1-hot) and masked at accumulate via cndmask.
// ---------------------------------------------------------------------------

constexpr int BN       = 512;       // nodes per bucket
constexpr int LOG_BN   = 9;
constexpr int MAXBUCK  = 512;       // supports N <= 262144 (src fits 18 bits)
constexpr int EPB      = 8192;      // edges per coarse block
constexpr int SRC_BITS = 18;
constexpr int SRC_MASK = (1 << SRC_BITS) - 1;
constexpr int BCAP_LOG = 14;        // padded bucket capacity 16384 (avg ~8184)

static __device__ inline float h2f(ushort u) {
    _Float16 h;
    __builtin_memcpy(&h, &u, 2);
    return (float)h;
}
static __device__ inline ushort f2h(float f) {
    _Float16 h = (_Float16)f;
    ushort u;
    __builtin_memcpy(&u, &h, 2);
    return u;
}

// One pass over edges: per-block LDS histogram -> reserve runs in padded
// bucket regions (bucket_cur also accumulates final counts) -> scatter packed.
__global__ __launch_bounds__(256)
void coarse_scatter(const int* __restrict__ src, const int* __restrict__ dst,
                    int* __restrict__ bucket_cur, int* __restrict__ packed,
                    int E, int nbuck) {
    __shared__ int h[MAXBUCK];
    int t = threadIdx.x;
    for (int i = t; i < nbuck; i += 256) h[i] = 0;
    __syncthreads();
    int base = blockIdx.x * EPB;
    int end  = min(base + EPB, E);
    for (int j = base + t; j < end; j += 256)
        atomicAdd(&h[dst[j] >> LOG_BN], 1);
    __syncthreads();
    for (int i = t; i < nbuck; i += 256) {
        int c = h[i];
        if (c) h[i] = atomicAdd(&bucket_cur[i], c);   // within-bucket offset
    }
    __syncthreads();
    for (int j = base + t; j < end; j += 256) {
        int d  = dst[j];
        int bk = d >> LOG_BN;
        int p  = atomicAdd(&h[bk], 1);
        packed[(bk << BCAP_LOG) + p] = ((d & (BN - 1)) << SRC_BITS) | src[j];
    }
}

__global__ __launch_bounds__(512)
void bucket_scan(const int* __restrict__ cnts, int* __restrict__ bucket_base,
                 int nbuck) {
    __shared__ int sh[512];
    int t = threadIdx.x;
    int v = (t < nbuck) ? cnts[t] : 0;
    sh[t] = v;
    __syncthreads();
    for (int off = 1; off < 512; off <<= 1) {
        int u = (t >= off) ? sh[t - off] : 0;
        __syncthreads();
        sh[t] += u;
        __syncthreads();
    }
    if (t < nbuck) bucket_base[t] = sh[t] - v;        // exclusive prefix
}

// One block per bucket: per-node count+scan+cursors in LDS; csr writes land
// in this block's contiguous output window.
__global__ __launch_bounds__(512)
void fine_fill(const int* __restrict__ packed, const int* __restrict__ bucket_cnt,
               const int* __restrict__ bucket_base, int* __restrict__ rowstart,
               int* __restrict__ csr, int N, int E) {
    __shared__ int cnt_[BN];
    __shared__ int cur_[BN];
    __shared__ int sh[512];
    int b = blockIdx.x, t = threadIdx.x;
    int cnt   = bucket_cnt[b];
    int obase = bucket_base[b];
    const int* __restrict__ pk = packed + ((size_t)b << BCAP_LOG);
    cnt_[t] = 0;
    __syncthreads();
    for (int j = t; j < cnt; j += 512)
        atomicAdd(&cnt_[pk[j] >> SRC_BITS], 1);
    __syncthreads();
    int v = cnt_[t];
    sh[t] = v;
    __syncthreads();
    for (int off = 1; off < 512; off <<= 1) {
        int u = (t >= off) ? sh[t - off] : 0;
        __syncthreads();
        sh[t] += u;
        __syncthreads();
    }
    int excl = sh[t] - v;
    int node = b * BN + t;
    if (node < N) rowstart[node] = obase + excl;
    cur_[t] = obase + excl;
    __syncthreads();
    for (int j = t; j < cnt; j += 512) {
        int pv = pk[j];
        int p  = atomicAdd(&cur_[pv >> SRC_BITS], 1);
        csr[p] = pv & SRC_MASK;
    }
    if (b == 0 && t == 0) rowstart[N] = E;
}

// f32 -> f16 convert (2 elems/thread), for the layer-0 input table.
__global__ __launch_bounds__(256)
void cvt_f32_f16(const float* __restrict__ in, ushort* __restrict__ out, int n2) {
    int i = blockIdx.x * 256 + threadIdx.x;
    if (i < n2) {
        float2 v = ((const float2*)in)[i];
        ushort2 o;
        o.x = f2h(v.x);
        o.y = f2h(v.y);
        ((ushort2*)out)[i] = o;
    }
}

// Fused SAGE layer: mean-aggregate + h@Ws + mean@Wn + b, tanh.
// Input features from f16 table ht_in [N][32]; f32 output into cs column
// slice; optionally writes next layer's f16 table.
template <int GROUPS, bool WRITE_F16>
__global__ __launch_bounds__(GROUPS * 32)
void sage_layer(const ushort* __restrict__ ht_in,
                float* __restrict__ h_out, int out_off,
                ushort* __restrict__ ht_out,
                const int* __restrict__ rowstart, const int* __restrict__ csr,
                const float* __restrict__ Ws, const float* __restrict__ Wn,
                const float* __restrict__ b, int N) {
    __shared__ float2 WS[32 * 32];       // interleaved (Ws, Wn)
    __shared__ float2 HM[GROUPS][32];    // per-group (h, mean) row
    __shared__ float  bS[32];

    int tid = threadIdx.x;
    for (int i = tid; i < 1024; i += GROUPS * 32)
        WS[i] = make_float2(Ws[i], Wn[i]);
    if (tid < 32) bS[tid] = b[tid];
    __syncthreads();

    int g = tid >> 5;
    int f = tid & 31;
    int n = blockIdx.x * GROUPS + g;
    if (n >= N) return;

    const ushort* __restrict__ hb = ht_in + f;   // per-lane base

    float hval = h2f(hb[(unsigned)(n << 5)]);

    int start = rowstart[n];
    int end   = rowstart[n + 1];
    float acc0 = 0.f, acc1 = 0.f;
    int j = start;
    while (j < end) {
        int rem = end - j;               // > 0
        // phase 1: csr chunk load + 16 batched bpermute broadcasts
        int cv = (f < 16 && f < rem) ? csr[j + f] : 0;
        int sidx[16];
#pragma unroll
        for (int k = 0; k < 16; ++k)
            sidx[k] = __shfl(cv, k, 32);     // dead k -> 0 (row 0, valid)
        // phase 2: 16 batched loads, branchless (dead lanes hit row 0, L1-hot)
        ushort u[16];
#pragma unroll
        for (int k = 0; k < 16; ++k)
            u[k] = hb[(unsigned)(sidx[k] << 5)];
        // phase 3: masked accumulate (cndmask, no branches)
#pragma unroll
        for (int k = 0; k < 16; k += 2) {
            acc0 += (k     < rem) ? h2f(u[k])     : 0.f;
            acc1 += (k + 1 < rem) ? h2f(u[k + 1]) : 0.f;
        }
        j += min(16, rem);
    }
    float acc = acc0 + acc1;

    int deg = end - start;
    float mval = acc / (float)(deg > 0 ? deg : 1);

    // share (h, mean) within the 32-lane group via LDS (same wave)
    HM[g][f] = make_float2(hval, mval);
    __builtin_amdgcn_wave_barrier();

    float out = bS[f];
#pragma unroll
    for (int k = 0; k < 32; ++k) {
        float2 hm = HM[g][k];            // broadcast
        float2 w  = WS[k * 32 + f];      // 8B stride, 2-way free
        out += hm.x * w.x + hm.y * w.y;
    }
    float r = tanhf(out);
    h_out[(unsigned)((n << 7) + out_off + f)] = r;
    if (WRITE_F16)
        ht_out[(unsigned)(n << 5) + f] = f2h(r);
}

// Pair MLP head: hdn = relu([cs[u], cs[i]] @ W1 + bl1); out = sigmoid(hdn@W2+bl2)
template <int PPB>
__global__ __launch_bounds__(128)
void pair_mlp(const float* __restrict__ cs, const int* __restrict__ uidx,
              const int* __restrict__ iidx, const float* __restrict__ W1,
              const float* __restrict__ bl1, const float* __restrict__ W2,
              const float* __restrict__ bl2, float* __restrict__ score, int P) {
    __shared__ float sp[PPB][256];
    __shared__ float wsum[2][PPB];
    int j  = threadIdx.x;
    int p0 = blockIdx.x * PPB;

    for (int q = 0; q < PPB; ++q) {
        int p = p0 + q;
        if (p < P) {
            int u  = uidx[p];
            int it = iidx[p];
            sp[q][j]       = cs[(size_t)u  * 128 + j];
            sp[q][128 + j] = cs[(size_t)it * 128 + j];
        } else {
            sp[q][j] = 0.f;
            sp[q][128 + j] = 0.f;
        }
    }
    __syncthreads();

    float acc[PPB];
    float bb = bl1[j];
#pragma unroll
    for (int q = 0; q < PPB; ++q) acc[q] = bb;

    for (int i = 0; i < 256; ++i) {
        float w = W1[i * 128 + j];
#pragma unroll
        for (int q = 0; q < PPB; ++q) acc[q] += sp[q][i] * w;
    }

    float w2   = W2[j];
    int   wave = j >> 6;
    int   lane = j & 63;
#pragma unroll
    for (int q = 0; q < PPB; ++q) {
        float v = fmaxf(acc[q], 0.f) * w2;
#pragma unroll
        for (int o = 32; o > 0; o >>= 1) v += __shfl_xor(v, o, 64);
        if (lane == 0) wsum[wave][q] = v;
    }
    __syncthreads();
    if (j < PPB) {
        int p = p0 + j;
        if (p < P) {
            float t = wsum[0][j] + wsum[1][j] + bl2[0];
            score[p] = 1.f / (1.f + expf(-t));
        }
    }
}

extern "C" void kernel_launch(void* const* d_in, const int* in_sizes, int n_in,
                              void* d_out, int out_size, void* d_ws, size_t ws_size,
                              hipStream_t stream) {
    const float* x    = (const float*)d_in[0];
    const int*   src  = (const int*)d_in[1];
    const int*   dst  = (const int*)d_in[2];
    const int*   uidx = (const int*)d_in[3];
    const int*   iidx = (const int*)d_in[4];
    const float* Ws[4] = {(const float*)d_in[5], (const float*)d_in[8],
                          (const float*)d_in[11], (const float*)d_in[14]};
    const float* Wn[4] = {(const float*)d_in[6], (const float*)d_in[9],
                          (const float*)d_in[12], (const float*)d_in[15]};
    const float* bb[4] = {(const float*)d_in[7], (const float*)d_in[10],
                          (const float*)d_in[13], (const float*)d_in[16]};
    const float* W1  = (const float*)d_in[17];
    const float* bl1 = (const float*)d_in[18];
    const float* W2  = (const float*)d_in[19];
    const float* bl2 = (const float*)d_in[20];

    const int N = in_sizes[0] / 32;
    const int E = in_sizes[1];
    const int P = in_sizes[3];
    const int NBUCK = (N + BN - 1) / BN;            // 391 for N=200k
    const int NEB   = (E + EPB - 1) / EPB;

    // workspace (ints): ~39 MB total
    int* ws_i        = (int*)d_ws;
    size_t o         = 0;
    int* bucket_cur  = ws_i + o; o += MAXBUCK;      // counts after scatter
    int* bucket_base = ws_i + o; o += MAXBUCK;
    int* rowstart    = ws_i + o; o += (size_t)((N + 1 + 63) & ~63);
    int* csr         = ws_i + o; o += (size_t)E;
    ushort* ht0      = (ushort*)(ws_i + o); o += (size_t)(N * 16);  // [N][32] f16
    ushort* ht1      = (ushort*)(ws_i + o); o += (size_t)(N * 16);

    float* score = (float*)d_out;
    float* cs    = score + P;                       // concat_states [N,128]
    // padded packed edges live in the tail of d_out: consumed by fine_fill
    // before any sage layer writes that region.
    int* packed  = (int*)d_out + ((size_t)out_size - ((size_t)NBUCK << BCAP_LOG));

    // --- build CSR (dst -> list of src) ---
    hipMemsetAsync(bucket_cur, 0, sizeof(int) * MAXBUCK, stream);
    coarse_scatter<<<NEB, 256, 0, stream>>>(src, dst, bucket_cur, packed, E, NBUCK);
    bucket_scan<<<1, 512, 0, stream>>>(bucket_cur, bucket_base, NBUCK);
    fine_fill<<<NBUCK, 512, 0, stream>>>(packed, bucket_cur, bucket_base,
                                         rowstart, csr, N, E);

    // --- layer-0 input table: x -> f16 ---
    cvt_f32_f16<<<(N * 16 + 255) / 256, 256, 0, stream>>>(x, ht0, N * 16);

    // --- 4 fused SAGE layers, writing concat_states slices + f16 tables ---
    sage_layer<8, true><<<(N + 7) / 8, 256, 0, stream>>>(
        ht0, cs, 0, ht1, rowstart, csr, Ws[0], Wn[0], bb[0], N);
    sage_layer<8, true><<<(N + 7) / 8, 256, 0, stream>>>(
        ht1, cs, 32, ht0, rowstart, csr, Ws[1], Wn[1], bb[1], N);
    sage_layer<8, true><<<(N + 7) / 8, 256, 0, stream>>>(
        ht0, cs, 64, ht1, rowstart, csr, Ws[2], Wn[2], bb[2], N);
    sage_layer<8, false><<<(N + 7) / 8, 256, 0, stream>>>(
        ht1, cs, 96, (ushort*)nullptr, rowstart, csr, Ws[3], Wn[3], bb[3], N);

    // --- pair MLP head ---
    pair_mlp<8><<<(P + 7) / 8, 128, 0, stream>>>(
        cs, uidx, iidx, W1, bl1, W2, bl2, score, P);
}